// Round 1
// baseline (421.844 us; speedup 1.0000x reference)
//
#include <hip/hip_runtime.h>

// CTC loss forward (alpha recursion), B=64, T=1024, C=128, L=256.
// One block per batch element; one thread per CTC state (S=513), 576 threads.
// Alpha double-buffered in LDS, one __syncthreads per time step.
// y_pred rows staged to LDS in 32-row chunks, double-buffered, loaded one
// chunk ahead so global latency is off the per-step critical path.

#define Bc 64
#define Tc 1024
#define Cc 128
#define Lc 256
#define Sc 513          // 2*L+1
#define BLANKc 127
#define CHUNK 32        // rows of y_pred staged per LDS chunk
#define NTHREADS 576    // 9 waves; one thread per state (513 active)

constexpr float NEGF = -1e30f;
constexpr float EPSF = 1e-7f;

__global__ __launch_bounds__(NTHREADS) void ctc_loss_kernel(
    const int* __restrict__ y_true,        // [B, L]
    const float* __restrict__ y_pred,      // [B, T, C]
    const int* __restrict__ input_length,  // [B, 1]
    const int* __restrict__ label_length,  // [B, 1]
    float* __restrict__ out)               // [B, 1]
{
    const int b = blockIdx.x;
    const int tid = threadIdx.x;

    __shared__ float sAlpha[2][Sc + 3];          // +pad
    __shared__ float sRows[2][CHUNK][Cc];        // 2 x 16 KB

    const int lab_len = label_length[b];
    const int in_len  = input_length[b];
    const float* yp = y_pred + (size_t)b * Tc * Cc;
    const int*   lab = y_true + b * Lc;

    // ---- per-thread state metadata (computed once) ----
    const int s = tid;
    const bool isState = (s < Sc);
    int  extc = BLANKc;
    bool skip = false;
    bool valid = false;
    if (isState) {
        if (s & 1) extc = lab[s >> 1];
        valid = (s < 2 * lab_len + 1);
        if ((s & 1) && s >= 2) {
            int prevLab = lab[(s >> 1) - 1];
            skip = (extc != BLANKc) && (extc != prevLab);
        }
    }

    // ---- preload chunk 0 and chunk 1 ----
    const float4* yp4 = (const float4*)yp;
    const int C4 = CHUNK * Cc / 4;   // float4s per chunk = 1024
    {
        float4* dst0 = (float4*)sRows[0];
        for (int i = tid; i < C4; i += NTHREADS) dst0[i] = yp4[i];
        float4* dst1 = (float4*)sRows[1];
        for (int i = tid; i < C4; i += NTHREADS) dst1[i] = yp4[C4 + i];
    }
    __syncthreads();

    // ---- t = 0 init ----
    if (isState) {
        float v = NEGF;
        if (valid) {
            if (s == 0)      v = __logf(sRows[0][0][BLANKc] + EPSF);
            else if (s == 1) v = (lab_len > 0) ? __logf(sRows[0][0][extc] + EPSF) : NEGF;
        }
        sAlpha[0][s] = v;
    }
    __syncthreads();

    // ---- main recursion t = 1 .. T-1 ----
    for (int t = 1; t < Tc; ++t) {
        const int k = t >> 5;                 // chunk index (CHUNK=32)

        // At the first step of chunk k, stage chunk k+1 into the other buffer.
        if ((t & (CHUNK - 1)) == 0) {
            const int kn = k + 1;
            if (kn < Tc / CHUNK) {
                const float4* src = yp4 + (size_t)kn * C4;
                float4* dst = (float4*)sRows[kn & 1];
                for (int i = tid; i < C4; i += NTHREADS) dst[i] = src[i];
            }
        }

        const float* row = sRows[k & 1][t & (CHUNK - 1)];
        const int prv = (t - 1) & 1;
        const int cur = t & 1;

        if (isState) {
            float a0 = sAlpha[prv][s];
            float nv;
            if (valid) {
                float a1 = (s >= 1) ? sAlpha[prv][s - 1] : NEGF;
                float a2 = skip     ? sAlpha[prv][s - 2] : NEGF;
                float m  = fmaxf(a0, fmaxf(a1, a2));
                float lse = m + __logf(__expf(a0 - m) + __expf(a1 - m) + __expf(a2 - m));
                float lp  = __logf(row[extc] + EPSF);
                nv = lse + lp;
                nv = (t < in_len) ? nv : a0;       // freeze past input_length
            } else {
                nv = (t < in_len) ? NEGF : a0;     // invalid states pinned at NEG
            }
            sAlpha[cur][s] = nv;
        }
        __syncthreads();
    }

    // ---- epilogue: loss = -logaddexp(alpha[T-1][2l], alpha[T-1][2l-1]) ----
    if (tid == 0) {
        const float* af = sAlpha[(Tc - 1) & 1];
        const int e1 = 2 * lab_len;
        const int e2 = (2 * lab_len - 1 > 0) ? (2 * lab_len - 1) : 0;
        float end_blank = af[e1];
        float end_label = (lab_len > 0) ? af[e2] : NEGF;
        float m = fmaxf(end_blank, end_label);
        float loss = -(m + __logf(__expf(end_blank - m) + __expf(end_label - m)));
        out[b] = loss;
    }
}

extern "C" void kernel_launch(void* const* d_in, const int* in_sizes, int n_in,
                              void* d_out, int out_size, void* d_ws, size_t ws_size,
                              hipStream_t stream) {
    const int*   y_true       = (const int*)d_in[0];
    const float* y_pred       = (const float*)d_in[1];
    const int*   input_length = (const int*)d_in[2];
    const int*   label_length = (const int*)d_in[3];
    float* out = (float*)d_out;

    ctc_loss_kernel<<<Bc, NTHREADS, 0, stream>>>(y_true, y_pred, input_length,
                                                 label_length, out);
}

// Round 4
// 221.147 us; speedup vs baseline: 1.9075x; 1.9075x over previous
//
#include <hip/hip_runtime.h>

// CTC loss forward, f64 prob-domain with power-of-2 rescaling.
// One WAVE (64 lanes) per batch element. Lane l holds states s=8l..8l+7 in
// f64 registers (+ state 512 as a 9th reg, meaningful on lane 63 only).
// No __syncthreads in the T-loop (single wave). Cross-lane: one __shfl_up
// per step (neighbor's old a7). y_pred staged to LDS via global_load_lds,
// 32-row chunks, double-buffered; p-gather prefetched one row ahead.
// Rescale every 8 steps: zero INVALID states (masking them out of the max
// anchor -- round 3's inf came from unmasked invalid states hijacking the
// anchor), then scale by 2^-e of the VALID wave-max exponent (int DPP
// reduce), exact in log space. f64 gives ~745 nats retention below the
// valid running max (f32's ~103 was insufficient: round 2 erred +128 nats).

#define Bc 64
#define Tc 1024
#define Cc 128
#define Lc 256
#define Sc 513
#define BLANKc 127
#define CHUNK 32
#define NCHUNK (Tc / CHUNK)

constexpr float EPSF = 1e-7f;

#define DPPMAXI(x, ctrl) max(x, __builtin_amdgcn_update_dpp( \
    0, x, ctrl, 0xf, 0xf, true))

__global__ __launch_bounds__(64) void ctc_kernel(
    const int* __restrict__ y_true,        // [B, L]
    const float* __restrict__ y_pred,      // [B, T, C]
    const int* __restrict__ input_length,  // [B, 1]
    const int* __restrict__ label_length,  // [B, 1]
    float* __restrict__ out)               // [B, 1]
{
    const int b = blockIdx.x;
    const int lane = threadIdx.x;          // 0..63, one wave per block

    __shared__ float rows[2][CHUNK * Cc];  // 2 x 16 KB staged y_pred rows
    __shared__ double afin[Sc];            // final alpha dump

    const int lab_len = label_length[b];
    const int in_len  = min(input_length[b], Tc);
    const float* yp = y_pred + (size_t)b * Tc * Cc;
    const int* lab = y_true + b * Lc;

    // ---- per-lane static metadata ----
    const int i0 = 4 * lane;               // label idx base for odd states
    const int c0 = lab[i0], c1 = lab[i0 + 1], c2 = lab[i0 + 2], c3 = lab[i0 + 3];
    const double sm0 = (lane == 0) ? 0.0
                       : ((c0 != BLANKc && c0 != lab[i0 - 1]) ? 1.0 : 0.0);
    const double sm1 = (c1 != BLANKc && c1 != c0) ? 1.0 : 0.0;
    const double sm2 = (c2 != BLANKc && c2 != c1) ? 1.0 : 0.0;
    const double sm3 = (c3 != BLANKc && c3 != c2) ? 1.0 : 0.0;

    // validity masks: state 8*lane+j valid iff < 2*lab_len+1
    const int S2 = 2 * lab_len + 1;
    double vm[8];
    #pragma unroll
    for (int j = 0; j < 8; ++j) vm[j] = (8 * lane + j < S2) ? 1.0 : 0.0;
    const double vm8 = (lane == 63 && 512 < S2) ? 1.0 : 0.0;

    // ---- staging: 16 KB chunk via global_load_lds (16 B/lane/instr) ----
    auto stage = [&](int k2, float* dstbuf) {
        const float* g = yp + (size_t)k2 * (CHUNK * Cc) + lane * 4;
        #pragma unroll
        for (int i = 0; i < 16; ++i) {
            __builtin_amdgcn_global_load_lds(
                (const __attribute__((address_space(1))) void*)(g + i * 256),
                (__attribute__((address_space(3))) void*)(dstbuf + i * 256),
                16, 0, 0);
        }
    };

    // ---- alpha registers (f64) ----
    double a0 = 0, a1 = 0, a2 = 0, a3 = 0, a4 = 0, a5 = 0, a6 = 0, a7 = 0, a8 = 0;

    float rawb, raw0, raw1, raw2, raw3;    // gathered f32 p for current row
    double peb, p1, p3, p5, p7;            // expanded (p+EPS) per class
    int tote = 0;                          // accumulated log2 scale removed

    auto gatherRow = [&](const float* rb, int r) {
        const float* row = rb + r * Cc;
        rawb = row[BLANKc];
        raw0 = row[c0]; raw1 = row[c1]; raw2 = row[c2]; raw3 = row[c3];
    };
    auto expand = [&]() {
        peb = (double)(rawb + EPSF);
        p1  = (double)(raw0 + EPSF);
        p3  = (double)(raw1 + EPSF);
        p5  = (double)(raw2 + EPSF);
        p7  = (double)(raw3 + EPSF);
    };
    auto stepfn = [&]() {
        double n7 = __shfl_up(a7, 1);      // neighbor's old a7 (= state s-1 of a0)
        n7 = (lane == 0) ? 0.0 : n7;
        a8 = (a8 + a7) * peb;              // state 512 (lane 63 only meaningful)
        a7 = (a7 + a6 + sm3 * a5) * p7;
        a6 = (a6 + a5) * peb;
        a5 = (a5 + a4 + sm2 * a3) * p5;
        a4 = (a4 + a3) * peb;
        a3 = (a3 + a2 + sm1 * a1) * p3;
        a2 = (a2 + a1) * peb;
        a1 = (a1 + a0 + sm0 * n7) * p1;
        a0 = (a0 + n7) * peb;
    };
    auto rescale = [&]() {
        // zero invalid states FIRST: they never feed valid states (flow is
        // strictly forward), but they must not set the rescale anchor.
        a0 *= vm[0]; a1 *= vm[1]; a2 *= vm[2]; a3 *= vm[3];
        a4 *= vm[4]; a5 *= vm[5]; a6 *= vm[6]; a7 *= vm[7];
        a8 *= vm8;
        double m = fmax(fmax(fmax(a0, a1), fmax(a2, a3)),
                        fmax(fmax(a4, a5), fmax(a6, fmax(a7, a8))));
        int e = (__double2hiint(m) >> 20) & 0x7ff;   // biased exponent (0 if m==0)
        e = DPPMAXI(e, 0x111);   // row_shr:1
        e = DPPMAXI(e, 0x112);   // row_shr:2
        e = DPPMAXI(e, 0x114);   // row_shr:4
        e = DPPMAXI(e, 0x118);   // row_shr:8
        e = DPPMAXI(e, 0x142);   // row_bcast:15
        e = DPPMAXI(e, 0x143);   // row_bcast:31
        const int emax = __builtin_amdgcn_readlane(e, 63);
        int sexp = 2046 - emax;                      // biased exp of 2^(1023-emax)
        sexp = min(max(sexp, 1), 2045);
        const double sc = __hiloint2double(sexp << 20, 0);   // exact power of 2
        tote += 1023 - sexp;                         // log2 of removed scale
        a0 *= sc; a1 *= sc; a2 *= sc; a3 *= sc; a4 *= sc;
        a5 *= sc; a6 *= sc; a7 *= sc; a8 *= sc;
    };

    // ---- stage chunk 0, init, start chunk 1 ----
    stage(0, rows[0]);
    __builtin_amdgcn_s_waitcnt(0);
    __syncthreads();
    stage(1, rows[1]);

    if (lane == 0) {
        a0 = (double)(rows[0][BLANKc] + EPSF);               // s=0
        if (lab_len > 0) a1 = (double)(rows[0][c0] + EPSF);  // s=1
    }
    gatherRow(rows[0], 1);           // raws for t=1

    // ---- chunk 0: rows 1..31 ----
    {
        const float* rb = rows[0];
        #pragma unroll 8
        for (int r = 1; r < CHUNK; ++r) {
            expand();
            if (r + 1 < CHUNK) gatherRow(rb, r + 1);
            if (r < in_len) stepfn();
            if ((r & 7) == 7) rescale();
        }
        __builtin_amdgcn_s_waitcnt(0);
        __syncthreads();             // chunk-1 loads landed
        stage(2, rows[0]);
        gatherRow(rows[1], 0);
    }

    // ---- chunks 1..31 ----
    for (int k = 1; k < NCHUNK; ++k) {
        const float* rb = rows[k & 1];
        const int tbase = k * CHUNK;
        #pragma unroll 8
        for (int r = 0; r < CHUNK; ++r) {
            expand();
            if (r + 1 < CHUNK) gatherRow(rb, r + 1);
            if (tbase + r < in_len) stepfn();
            if ((r & 7) == 7) rescale();
        }
        __builtin_amdgcn_s_waitcnt(0);
        __syncthreads();             // chunk k+1 loads landed
        if (k + 2 < NCHUNK) stage(k + 2, rows[k & 1]);
        if (k + 1 < NCHUNK) gatherRow(rows[(k + 1) & 1], 0);
    }

    // ---- epilogue ----
    afin[8 * lane + 0] = a0; afin[8 * lane + 1] = a1;
    afin[8 * lane + 2] = a2; afin[8 * lane + 3] = a3;
    afin[8 * lane + 4] = a4; afin[8 * lane + 5] = a5;
    afin[8 * lane + 6] = a6; afin[8 * lane + 7] = a7;
    if (lane == 63) afin[512] = a8;
    __syncthreads();
    if (lane == 0) {
        const double eb = afin[2 * lab_len];
        const double el = (lab_len > 0) ? afin[2 * lab_len - 1] : 0.0;
        const double loss = -(log(eb + el) + (double)tote * 0.6931471805599453);
        out[b] = (float)loss;
    }
}

extern "C" void kernel_launch(void* const* d_in, const int* in_sizes, int n_in,
                              void* d_out, int out_size, void* d_ws, size_t ws_size,
                              hipStream_t stream) {
    const int*   y_true       = (const int*)d_in[0];
    const float* y_pred       = (const float*)d_in[1];
    const int*   input_length = (const int*)d_in[2];
    const int*   label_length = (const int*)d_in[3];
    float* out = (float*)d_out;

    ctc_kernel<<<Bc, 64, 0, stream>>>(y_true, y_pred, input_length,
                                      label_length, out);
}

// Round 5
// 189.448 us; speedup vs baseline: 2.2267x; 1.1673x over previous
//
#include <hip/hip_runtime.h>

// CTC loss forward, f64 prob-domain with power-of-2 rescaling.
// One WAVE (64 lanes) per batch element. Lane l holds states s=8l..8l+7 in
// f64 registers (+ state 512 on lane 63). No barriers, no bpermute in the
// T-loop: cross-lane neighbor via DPP wave_shr:1 (pure VALU), so the only
// lgkm waits are the distance-2-prefetched LDS gathers (fully covered).
// y_pred staged to LDS via global_load_lds, 32-row chunks, TRIPLE-buffered;
// chunk-boundary sync is a vmcnt-only s_waitcnt (single wave per block).
// Rescale every 8 steps: zero invalid states (they must not set the anchor
// -- round-3 inf), then scale by 2^-e of the valid wave-max exponent (int
// DPP reduce), exact in log space. f64 gives ~745 nats retention below the
// valid running max (f32's ~103 was insufficient -- round-2 +128-nat error).

#define Bc 64
#define Tc 1024
#define Cc 128
#define Lc 256
#define Sc 513
#define BLANKc 127
#define CHUNK 32
#define NCHUNK (Tc / CHUNK)

constexpr float EPSF = 1e-7f;

#define DPPMAXI(x, ctrl) max(x, __builtin_amdgcn_update_dpp( \
    0, x, ctrl, 0xf, 0xf, true))

__device__ __forceinline__ double dpp_wave_shr1_f64(double x) {
    // lane l receives lane l-1's value; lane 0 receives 0 (bound_ctrl).
    union { double d; int i[2]; } u, r;
    u.d = x;
    r.i[0] = __builtin_amdgcn_update_dpp(0, u.i[0], 0x138, 0xf, 0xf, true);
    r.i[1] = __builtin_amdgcn_update_dpp(0, u.i[1], 0x138, 0xf, 0xf, true);
    return r.d;
}

__global__ __launch_bounds__(64) void ctc_kernel(
    const int* __restrict__ y_true,        // [B, L]
    const float* __restrict__ y_pred,      // [B, T, C]
    const int* __restrict__ input_length,  // [B, 1]
    const int* __restrict__ label_length,  // [B, 1]
    float* __restrict__ out)               // [B, 1]
{
    const int b = blockIdx.x;
    const int lane = threadIdx.x;          // 0..63, one wave per block

    __shared__ float bufs[3][CHUNK * Cc];  // 3 x 16 KB staged y_pred rows
    __shared__ double afin[Sc];            // final alpha dump

    const int lab_len = label_length[b];
    const int in_len  = min(input_length[b], Tc);
    const float* yp = y_pred + (size_t)b * Tc * Cc;
    const int* lab = y_true + b * Lc;

    // ---- per-lane static metadata ----
    const int i0 = 4 * lane;               // label idx base for odd states
    const int c0 = lab[i0], c1 = lab[i0 + 1], c2 = lab[i0 + 2], c3 = lab[i0 + 3];
    const double sm0 = (lane == 0) ? 0.0
                       : ((c0 != BLANKc && c0 != lab[i0 - 1]) ? 1.0 : 0.0);
    const double sm1 = (c1 != BLANKc && c1 != c0) ? 1.0 : 0.0;
    const double sm2 = (c2 != BLANKc && c2 != c1) ? 1.0 : 0.0;
    const double sm3 = (c3 != BLANKc && c3 != c2) ? 1.0 : 0.0;

    const int S2 = 2 * lab_len + 1;        // validity: state < S2
    double vm[8];
    #pragma unroll
    for (int j = 0; j < 8; ++j) vm[j] = (8 * lane + j < S2) ? 1.0 : 0.0;
    const double vm8 = (lane == 63 && 512 < S2) ? 1.0 : 0.0;

    // ---- staging: 16 KB chunk via global_load_lds (16 B/lane/instr) ----
    auto stage = [&](int k2, float* dstbuf) {
        const float* g = yp + (size_t)k2 * (CHUNK * Cc) + lane * 4;
        #pragma unroll
        for (int i = 0; i < 16; ++i) {
            __builtin_amdgcn_global_load_lds(
                (const __attribute__((address_space(1))) void*)(g + i * 256),
                (__attribute__((address_space(3))) void*)(dstbuf + i * 256),
                16, 0, 0);
        }
    };

    // ---- alpha registers (f64) ----
    double a0 = 0, a1 = 0, a2 = 0, a3 = 0, a4 = 0, a5 = 0, a6 = 0, a7 = 0, a8 = 0;

    // two raw-gather slots: slot parity = row & 1 (distance-2 prefetch)
    float rA[5], rB[5];
    double peb, p1, p3, p5, p7;
    int tote = 0;                          // accumulated log2 scale removed

    auto gather = [&](const float* rowp, float* slot) {
        slot[0] = rowp[BLANKc];
        slot[1] = rowp[c0]; slot[2] = rowp[c1];
        slot[3] = rowp[c2]; slot[4] = rowp[c3];
    };
    auto expand = [&](const float* slot) {
        peb = (double)(slot[0] + EPSF);
        p1  = (double)(slot[1] + EPSF);
        p3  = (double)(slot[2] + EPSF);
        p5  = (double)(slot[3] + EPSF);
        p7  = (double)(slot[4] + EPSF);
    };
    auto stepfn = [&]() {
        double n7 = dpp_wave_shr1_f64(a7); // neighbor's old a7 (lane0 -> 0)
        a8 = (a8 + a7) * peb;              // state 512 (lane 63 meaningful)
        a7 = (a7 + a6 + sm3 * a5) * p7;
        a6 = (a6 + a5) * peb;
        a5 = (a5 + a4 + sm2 * a3) * p5;
        a4 = (a4 + a3) * peb;
        a3 = (a3 + a2 + sm1 * a1) * p3;
        a2 = (a2 + a1) * peb;
        a1 = (a1 + a0 + sm0 * n7) * p1;
        a0 = (a0 + n7) * peb;
    };
    auto rescale = [&]() {
        // zero invalid states FIRST (never feed valid states; must not
        // hijack the rescale anchor), then remove the valid-max exponent.
        a0 *= vm[0]; a1 *= vm[1]; a2 *= vm[2]; a3 *= vm[3];
        a4 *= vm[4]; a5 *= vm[5]; a6 *= vm[6]; a7 *= vm[7];
        a8 *= vm8;
        double m = fmax(fmax(fmax(a0, a1), fmax(a2, a3)),
                        fmax(fmax(a4, a5), fmax(a6, fmax(a7, a8))));
        int e = (__double2hiint(m) >> 20) & 0x7ff;   // biased exp (0 if m==0)
        e = DPPMAXI(e, 0x111);   // row_shr:1
        e = DPPMAXI(e, 0x112);   // row_shr:2
        e = DPPMAXI(e, 0x114);   // row_shr:4
        e = DPPMAXI(e, 0x118);   // row_shr:8
        e = DPPMAXI(e, 0x142);   // row_bcast:15
        e = DPPMAXI(e, 0x143);   // row_bcast:31
        const int emax = __builtin_amdgcn_readlane(e, 63);
        int sexp = 2046 - emax;                      // biased exp of 2^(1023-emax)
        sexp = min(max(sexp, 1), 2045);
        const double sc = __hiloint2double(sexp << 20, 0);   // exact power of 2
        tote += 1023 - sexp;
        a0 *= sc; a1 *= sc; a2 *= sc; a3 *= sc; a4 *= sc;
        a5 *= sc; a6 *= sc; a7 *= sc; a8 *= sc;
    };

    // ---- prologue: stage chunks 0..2, init t=0, prime gather pipeline ----
    stage(0, bufs[0]);
    stage(1, bufs[1]);
    stage(2, bufs[2]);
    __builtin_amdgcn_s_waitcnt(0x0F70);  // vmcnt(0) only: DMA landed; 1 wave -> no barrier

    if (lane == 0) {
        a0 = (double)(bufs[0][BLANKc] + EPSF);               // s=0
        if (lab_len > 0) a1 = (double)(bufs[0][c0] + EPSF);  // s=1
    }
    gather(bufs[0] + 1 * Cc, rB);        // row 1 -> slot parity 1
    gather(bufs[0] + 2 * Cc, rA);        // row 2 -> slot parity 0

    // ---- chunk 0: rows 1..31 ----
    {
        const float* rb  = bufs[0];
        const float* rbn = bufs[1];
        #pragma unroll
        for (int r = 1; r < CHUNK; ++r) {
            float* cur = (r & 1) ? rB : rA;
            expand(cur);                 // consume row r
            const float* nxt = (r + 2 < CHUNK) ? (rb + (r + 2) * Cc)
                                               : (rbn + (r + 2 - CHUNK) * Cc);
            gather(nxt, cur);            // prefetch row r+2 into freed slot
            if (r < in_len) stepfn();
            if ((r & 7) == 7) rescale();
        }
    }
    __builtin_amdgcn_s_waitcnt(0x0F70);  // chunk-2 staging landed
    stage(3, bufs[0]);

    // ---- chunks 1..31 ----
    for (int k = 1; k < NCHUNK; ++k) {
        const float* rb  = bufs[k % 3];
        const float* rbn = bufs[(k + 1) % 3];  // k=31: stale buf, dead gathers
        const int tbase = k * CHUNK;
        #pragma unroll
        for (int r = 0; r < CHUNK; ++r) {
            float* cur = (r & 1) ? rB : rA;
            expand(cur);
            const float* nxt = (r + 2 < CHUNK) ? (rb + (r + 2) * Cc)
                                               : (rbn + (r + 2 - CHUNK) * Cc);
            gather(nxt, cur);
            if (tbase + r < in_len) stepfn();
            if ((r & 7) == 7) rescale();
        }
        __builtin_amdgcn_s_waitcnt(0x0F70);    // stage(k+2) landed
        if (k + 3 < NCHUNK) stage(k + 3, bufs[(k + 3) % 3]);
    }

    // ---- epilogue ----
    afin[8 * lane + 0] = a0; afin[8 * lane + 1] = a1;
    afin[8 * lane + 2] = a2; afin[8 * lane + 3] = a3;
    afin[8 * lane + 4] = a4; afin[8 * lane + 5] = a5;
    afin[8 * lane + 6] = a6; afin[8 * lane + 7] = a7;
    if (lane == 63) afin[512] = a8;
    __syncthreads();
    if (lane == 0) {
        const double eb = afin[2 * lab_len];
        const double el = (lab_len > 0) ? afin[2 * lab_len - 1] : 0.0;
        const double loss = -(log(eb + el) + (double)tote * 0.6931471805599453);
        out[b] = (float)loss;
    }
}

extern "C" void kernel_launch(void* const* d_in, const int* in_sizes, int n_in,
                              void* d_out, int out_size, void* d_ws, size_t ws_size,
                              hipStream_t stream) {
    const int*   y_true       = (const int*)d_in[0];
    const float* y_pred       = (const float*)d_in[1];
    const int*   input_length = (const int*)d_in[2];
    const int*   label_length = (const int*)d_in[3];
    float* out = (float*)d_out;

    ctc_kernel<<<Bc, 64, 0, stream>>>(y_true, y_pred, input_length,
                                      label_length, out);
}

// Round 6
// 154.012 us; speedup vs baseline: 2.7390x; 1.2301x over previous
//
#include <hip/hip_runtime.h>

// CTC loss forward, f64 prob-domain with power-of-2 rescaling.
// One WAVE per batch element; lane l holds states 8l..8l+7 (+513th on lane63)
// in f64 regs. No barriers / no bpermute in the T-loop: neighbor via DPP
// wave_shr:1. y_pred staged via global_load_lds into 3x16KB LDS buffers.
// Gathers fetch ROW PAIRS with ds_read2_b32 (offsets c, c+128 dwords),
// prefetched 2 pairs (4 rows) ahead. Rescale every 16 steps: int-exponent
// masked max (invalid states excluded from the anchor but NOT zeroed --
// they only flow forward and may harmlessly saturate), exact 2^-e scaling.
// f64 retention ~1022 bits below anchor vs needed ~560 worst-case.

#define Bc 64
#define Tc 1024
#define Cc 128
#define Lc 256
#define Sc 513
#define BLANKc 127
#define CHUNK 32
#define NCHUNK (Tc / CHUNK)

constexpr float EPSF = 1e-7f;

#define DPPMAXI(x, ctrl) max(x, __builtin_amdgcn_update_dpp( \
    0, x, ctrl, 0xf, 0xf, true))

__device__ __forceinline__ double dpp_wave_shr1_f64(double x) {
    // lane l <- lane l-1; lane 0 <- 0 (bound_ctrl)
    union { double d; int i[2]; } u, r;
    u.d = x;
    r.i[0] = __builtin_amdgcn_update_dpp(0, u.i[0], 0x138, 0xf, 0xf, true);
    r.i[1] = __builtin_amdgcn_update_dpp(0, u.i[1], 0x138, 0xf, 0xf, true);
    return r.d;
}

__global__ __launch_bounds__(64) void ctc_kernel(
    const int* __restrict__ y_true,        // [B, L]
    const float* __restrict__ y_pred,      // [B, T, C]
    const int* __restrict__ input_length,  // [B, 1]
    const int* __restrict__ label_length,  // [B, 1]
    float* __restrict__ out)               // [B, 1]
{
    const int b = blockIdx.x;
    const int lane = threadIdx.x;          // 0..63, one wave per block

    __shared__ float bufs[3][CHUNK * Cc];  // 3 x 16 KB staged y_pred rows
    __shared__ double afin[Sc];

    const int lab_len = label_length[b];
    const int in_len  = min(input_length[b], Tc);
    const float* yp = y_pred + (size_t)b * Tc * Cc;
    const int* lab = y_true + b * Lc;

    // ---- per-lane static metadata ----
    const int i0 = 4 * lane;
    const int c0 = lab[i0], c1 = lab[i0 + 1], c2 = lab[i0 + 2], c3 = lab[i0 + 3];
    const double sm0 = (lane == 0) ? 0.0
                       : ((c0 != BLANKc && c0 != lab[i0 - 1]) ? 1.0 : 0.0);
    const double sm1 = (c1 != BLANKc && c1 != c0) ? 1.0 : 0.0;
    const double sm2 = (c2 != BLANKc && c2 != c1) ? 1.0 : 0.0;
    const double sm3 = (c3 != BLANKc && c3 != c2) ? 1.0 : 0.0;

    const int S2 = 2 * lab_len + 1;        // validity: state < S2
    int ivm[8];
    #pragma unroll
    for (int j = 0; j < 8; ++j) ivm[j] = (8 * lane + j < S2) ? -1 : 0;
    const int ivm8 = (lane == 63 && 512 < S2) ? -1 : 0;

    auto stage = [&](int k2, float* dstbuf) {
        const float* g = yp + (size_t)k2 * (CHUNK * Cc) + lane * 4;
        #pragma unroll
        for (int i = 0; i < 16; ++i) {
            __builtin_amdgcn_global_load_lds(
                (const __attribute__((address_space(1))) void*)(g + i * 256),
                (__attribute__((address_space(3))) void*)(dstbuf + i * 256),
                16, 0, 0);
        }
    };

    // ---- alpha registers (f64) ----
    double a0 = 0, a1 = 0, a2 = 0, a3 = 0, a4 = 0, a5 = 0, a6 = 0, a7 = 0, a8 = 0;
    double peb, p1, p3, p5, p7;
    int tote = 0;

    // pair slots: even idx = row r, odd idx = row r+1 (ds_read2-friendly)
    float s01[10], s23[10];

    auto gpair = [&](const float* rowp, float* sl) {
        sl[0] = rowp[BLANKc]; sl[1] = rowp[BLANKc + Cc];
        sl[2] = rowp[c0];     sl[3] = rowp[c0 + Cc];
        sl[4] = rowp[c1];     sl[5] = rowp[c1 + Cc];
        sl[6] = rowp[c2];     sl[7] = rowp[c2 + Cc];
        sl[8] = rowp[c3];     sl[9] = rowp[c3 + Cc];
    };
    auto g1 = [&](const float* rowp, float* sl) {   // single row -> even idx
        sl[0] = rowp[BLANKc]; sl[2] = rowp[c0]; sl[4] = rowp[c1];
        sl[6] = rowp[c2];     sl[8] = rowp[c3];
    };
    auto expandEven = [&](const float* sl) {
        peb = (double)(sl[0] + EPSF); p1 = (double)(sl[2] + EPSF);
        p3  = (double)(sl[4] + EPSF); p5 = (double)(sl[6] + EPSF);
        p7  = (double)(sl[8] + EPSF);
    };
    auto expandOdd = [&](const float* sl) {
        peb = (double)(sl[1] + EPSF); p1 = (double)(sl[3] + EPSF);
        p3  = (double)(sl[5] + EPSF); p5 = (double)(sl[7] + EPSF);
        p7  = (double)(sl[9] + EPSF);
    };
    auto stepfn = [&]() {
        double n7 = dpp_wave_shr1_f64(a7);
        a8 = (a8 + a7) * peb;
        a7 = (a7 + a6 + sm3 * a5) * p7;
        a6 = (a6 + a5) * peb;
        a5 = (a5 + a4 + sm2 * a3) * p5;
        a4 = (a4 + a3) * peb;
        a3 = (a3 + a2 + sm1 * a1) * p3;
        a2 = (a2 + a1) * peb;
        a1 = (a1 + a0 + sm0 * n7) * p1;
        a0 = (a0 + n7) * peb;
    };
    auto rescale = [&]() {
        // masked int-exponent max over VALID states only (invalid may be
        // inf/NaN -- harmless, strictly-forward flow; just exclude from anchor)
        int e;
        e =        ivm[0] & (__double2hiint(a0) >> 20);
        e = max(e, ivm[1] & (__double2hiint(a1) >> 20));
        e = max(e, ivm[2] & (__double2hiint(a2) >> 20));
        e = max(e, ivm[3] & (__double2hiint(a3) >> 20));
        e = max(e, ivm[4] & (__double2hiint(a4) >> 20));
        e = max(e, ivm[5] & (__double2hiint(a5) >> 20));
        e = max(e, ivm[6] & (__double2hiint(a6) >> 20));
        e = max(e, ivm[7] & (__double2hiint(a7) >> 20));
        e = max(e, ivm8   & (__double2hiint(a8) >> 20));
        e = DPPMAXI(e, 0x111);   // row_shr:1
        e = DPPMAXI(e, 0x112);   // row_shr:2
        e = DPPMAXI(e, 0x114);   // row_shr:4
        e = DPPMAXI(e, 0x118);   // row_shr:8
        e = DPPMAXI(e, 0x142);   // row_bcast:15
        e = DPPMAXI(e, 0x143);   // row_bcast:31
        const int emax = __builtin_amdgcn_readlane(e, 63);
        int sexp = 2046 - emax;                      // biased exp of 2^(1023-emax)
        sexp = min(max(sexp, 1), 2045);
        const double sc = __hiloint2double(sexp << 20, 0);   // exact power of 2
        tote += 1023 - sexp;
        a0 *= sc; a1 *= sc; a2 *= sc; a3 *= sc; a4 *= sc;
        a5 *= sc; a6 *= sc; a7 *= sc; a8 *= sc;
    };

    // ---- prologue ----
    stage(0, bufs[0]);
    stage(1, bufs[1]);
    stage(2, bufs[2]);
    __builtin_amdgcn_s_waitcnt(0x0F70);  // vmcnt(0): DMA landed; 1 wave, no barrier

    if (lane == 0) {
        a0 = (double)(bufs[0][BLANKc] + EPSF);               // s=0
        if (lab_len > 0) a1 = (double)(bufs[0][c0] + EPSF);  // s=1
    }
    g1(bufs[0] + 1 * Cc, s23);           // row 1 (parity 1)
    g1(bufs[0] + 2 * Cc, s01);           // row 2 (parity 0)

    // ---- chunk 0: rows 1..31, single-row pipeline ----
    {
        const float* rb = bufs[0];
        #pragma unroll
        for (int r = 1; r < CHUNK; ++r) {
            float* cur = (r & 1) ? s23 : s01;
            expandEven(cur);
            if (r + 2 < CHUNK) g1(rb + (r + 2) * Cc, cur);
            if (r < in_len) stepfn();
            if ((r & 15) == 15) rescale();
        }
    }
    // prime pair pipeline for chunk 1 (bufs[1] landed at prologue wait)
    gpair(bufs[1] + 0 * Cc, s01);        // rows 0,1 of chunk 1
    gpair(bufs[1] + 2 * Cc, s23);        // rows 2,3 of chunk 1
    __builtin_amdgcn_s_waitcnt(0x0F70);
    stage(3, bufs[0]);

    // ---- chunks 1..31: pair pipeline ----
    for (int k = 1; k < NCHUNK; ++k) {
        const float* rb  = bufs[k % 3];
        const float* rbn = bufs[(k + 1) % 3];   // k=31: dead gathers, safe
        const int tbase = k * CHUNK;
        if (tbase + CHUNK <= in_len) {
            // fast path: whole chunk inside input length, branchless
            #pragma unroll
            for (int pr = 0; pr < 16; ++pr) {
                const int r = 2 * pr;
                float* cur = (pr & 1) ? s23 : s01;
                expandEven(cur); stepfn();
                expandOdd(cur);  stepfn();
                const float* nxt = (r + 4 < CHUNK) ? (rb + (r + 4) * Cc)
                                                   : (rbn + (r + 4 - CHUNK) * Cc);
                gpair(nxt, cur);             // prefetch rows r+4, r+5
                if ((pr & 7) == 7) rescale();
            }
        } else {
            #pragma unroll 2
            for (int pr = 0; pr < 16; ++pr) {
                const int r = 2 * pr;
                float* cur = (pr & 1) ? s23 : s01;
                expandEven(cur); if (tbase + r     < in_len) stepfn();
                expandOdd(cur);  if (tbase + r + 1 < in_len) stepfn();
                const float* nxt = (r + 4 < CHUNK) ? (rb + (r + 4) * Cc)
                                                   : (rbn + (r + 4 - CHUNK) * Cc);
                gpair(nxt, cur);
                if ((pr & 7) == 7) rescale();
            }
        }
        __builtin_amdgcn_s_waitcnt(0x0F70);     // stage(k+2) landed
        if (k + 3 < NCHUNK) stage(k + 3, bufs[(k + 3) % 3]);
    }

    // ---- epilogue ----
    afin[8 * lane + 0] = a0; afin[8 * lane + 1] = a1;
    afin[8 * lane + 2] = a2; afin[8 * lane + 3] = a3;
    afin[8 * lane + 4] = a4; afin[8 * lane + 5] = a5;
    afin[8 * lane + 6] = a6; afin[8 * lane + 7] = a7;
    if (lane == 63) afin[512] = a8;
    __syncthreads();
    if (lane == 0) {
        const double eb = afin[2 * lab_len];
        const double el = (lab_len > 0) ? afin[2 * lab_len - 1] : 0.0;
        const double loss = -(log(eb + el) + (double)tote * 0.6931471805599453);
        out[b] = (float)loss;
    }
}

extern "C" void kernel_launch(void* const* d_in, const int* in_sizes, int n_in,
                              void* d_out, int out_size, void* d_ws, size_t ws_size,
                              hipStream_t stream) {
    const int*   y_true       = (const int*)d_in[0];
    const float* y_pred       = (const float*)d_in[1];
    const int*   input_length = (const int*)d_in[2];
    const int*   label_length = (const int*)d_in[3];
    float* out = (float*)d_out;

    ctc_kernel<<<Bc, 64, 0, stream>>>(y_true, y_pred, input_length,
                                      label_length, out);
}

// Round 7
// 149.839 us; speedup vs baseline: 2.8153x; 1.0278x over previous
//
#include <hip/hip_runtime.h>

// CTC loss forward, f64 prob-domain with power-of-2 rescaling.
// One WAVE per batch element; lane l holds states 8l..8l+7 (+state 512 on
// lane 63) in f64 regs. No barriers/bpermute in T-loop; neighbor via DPP
// wave_shr:1, PIPELINED (n7 computed right after a7 so the cross-step chain
// has a full step of slack). stepfn is two-phase (all sums, then all muls)
// to expose the 9 independent per-state chains to the scheduler.
// y_pred staged via global_load_lds into 3x16KB LDS buffers; pair-row
// gathers (ds_read2-friendly), prefetched 2 pairs ahead. Rescale once per
// 32-step chunk at the chunk boundary: int-exponent masked max (invalid
// states excluded from anchor, not zeroed -- strictly-forward flow), exact
// 2^-e scaling. f64 window ~1022 bits vs ~800 worst-case need.

#define Bc 64
#define Tc 1024
#define Cc 128
#define Lc 256
#define Sc 513
#define BLANKc 127
#define CHUNK 32
#define NCHUNK (Tc / CHUNK)

constexpr float EPSF = 1e-7f;

#define DPPMAXI(x, ctrl) max(x, __builtin_amdgcn_update_dpp( \
    0, x, ctrl, 0xf, 0xf, true))

__device__ __forceinline__ double dpp_wave_shr1_f64(double x) {
    // lane l <- lane l-1; lane 0 <- 0 (bound_ctrl)
    union { double d; int i[2]; } u, r;
    u.d = x;
    r.i[0] = __builtin_amdgcn_update_dpp(0, u.i[0], 0x138, 0xf, 0xf, true);
    r.i[1] = __builtin_amdgcn_update_dpp(0, u.i[1], 0x138, 0xf, 0xf, true);
    return r.d;
}

__global__ __launch_bounds__(64) void ctc_kernel(
    const int* __restrict__ y_true,        // [B, L]
    const float* __restrict__ y_pred,      // [B, T, C]
    const int* __restrict__ input_length,  // [B, 1]
    const int* __restrict__ label_length,  // [B, 1]
    float* __restrict__ out)               // [B, 1]
{
    const int b = blockIdx.x;
    const int lane = threadIdx.x;          // 0..63, one wave per block

    __shared__ float bufs[3][CHUNK * Cc];  // 3 x 16 KB staged y_pred rows
    __shared__ double afin[Sc];

    const int lab_len = label_length[b];
    const int in_len  = min(input_length[b], Tc);
    const float* yp = y_pred + (size_t)b * Tc * Cc;
    const int* lab = y_true + b * Lc;

    // ---- per-lane static metadata ----
    const int i0 = 4 * lane;
    const int c0 = lab[i0], c1 = lab[i0 + 1], c2 = lab[i0 + 2], c3 = lab[i0 + 3];
    const double sm0 = (lane == 0) ? 0.0
                       : ((c0 != BLANKc && c0 != lab[i0 - 1]) ? 1.0 : 0.0);
    const double sm1 = (c1 != BLANKc && c1 != c0) ? 1.0 : 0.0;
    const double sm2 = (c2 != BLANKc && c2 != c1) ? 1.0 : 0.0;
    const double sm3 = (c3 != BLANKc && c3 != c2) ? 1.0 : 0.0;

    const int S2 = 2 * lab_len + 1;        // validity: state < S2
    int ivm[8];
    #pragma unroll
    for (int j = 0; j < 8; ++j) ivm[j] = (8 * lane + j < S2) ? -1 : 0;
    const int ivm8 = (lane == 63 && 512 < S2) ? -1 : 0;

    auto stage = [&](int k2, float* dstbuf) {
        const float* g = yp + (size_t)k2 * (CHUNK * Cc) + lane * 4;
        #pragma unroll
        for (int i = 0; i < 16; ++i) {
            __builtin_amdgcn_global_load_lds(
                (const __attribute__((address_space(1))) void*)(g + i * 256),
                (__attribute__((address_space(3))) void*)(dstbuf + i * 256),
                16, 0, 0);
        }
    };

    // ---- alpha registers (f64) ----
    double a0 = 0, a1 = 0, a2 = 0, a3 = 0, a4 = 0, a5 = 0, a6 = 0, a7 = 0, a8 = 0;
    double n7 = 0;                         // pipelined dpp(a7) from prev step
    double peb, p1, p3, p5, p7;
    int tote = 0;

    // pair slots: even idx = row r, odd idx = row r+1 (ds_read2-friendly)
    float s01[10], s23[10], sE[10];

    auto gpair = [&](const float* rowp, float* sl) {
        sl[0] = rowp[BLANKc]; sl[1] = rowp[BLANKc + Cc];
        sl[2] = rowp[c0];     sl[3] = rowp[c0 + Cc];
        sl[4] = rowp[c1];     sl[5] = rowp[c1 + Cc];
        sl[6] = rowp[c2];     sl[7] = rowp[c2 + Cc];
        sl[8] = rowp[c3];     sl[9] = rowp[c3 + Cc];
    };
    auto g1 = [&](const float* rowp, float* sl) {
        sl[0] = rowp[BLANKc]; sl[2] = rowp[c0]; sl[4] = rowp[c1];
        sl[6] = rowp[c2];     sl[8] = rowp[c3];
    };
    auto expandEven = [&](const float* sl) {
        const float fb = sl[0] + EPSF, f1 = sl[2] + EPSF, f3 = sl[4] + EPSF,
                    f5 = sl[6] + EPSF, f7 = sl[8] + EPSF;
        peb = (double)fb; p1 = (double)f1; p3 = (double)f3;
        p5 = (double)f5;  p7 = (double)f7;
    };
    auto expandOdd = [&](const float* sl) {
        const float fb = sl[1] + EPSF, f1 = sl[3] + EPSF, f3 = sl[5] + EPSF,
                    f5 = sl[7] + EPSF, f7 = sl[9] + EPSF;
        peb = (double)fb; p1 = (double)f1; p3 = (double)f3;
        p5 = (double)f5;  p7 = (double)f7;
    };
    auto stepfn = [&]() {
        // phase 1: all sums -- 9 independent chains (read only OLD values)
        const double t8 = a8 + a7;
        const double t7 = __fma_rn(sm3, a5, a7 + a6);
        const double t6 = a6 + a5;
        const double t5 = __fma_rn(sm2, a3, a5 + a4);
        const double t4 = a4 + a3;
        const double t3 = __fma_rn(sm1, a1, a3 + a2);
        const double t2 = a2 + a1;
        const double t1 = __fma_rn(sm0, n7, a1 + a0);
        const double t0 = a0 + n7;
        // phase 2: all muls -- independent
        a7 = t7 * p7;
        n7 = dpp_wave_shr1_f64(a7);        // pipelined: full step of slack
        a8 = t8 * peb; a6 = t6 * peb; a5 = t5 * p5; a4 = t4 * peb;
        a3 = t3 * p3;  a2 = t2 * peb; a1 = t1 * p1; a0 = t0 * peb;
    };
    auto rescale = [&]() {
        // masked int-exponent max over VALID states only (invalid may
        // saturate harmlessly -- strictly-forward flow; exclude from anchor)
        int e;
        e =        ivm[0] & (__double2hiint(a0) >> 20);
        e = max(e, ivm[1] & (__double2hiint(a1) >> 20));
        e = max(e, ivm[2] & (__double2hiint(a2) >> 20));
        e = max(e, ivm[3] & (__double2hiint(a3) >> 20));
        e = max(e, ivm[4] & (__double2hiint(a4) >> 20));
        e = max(e, ivm[5] & (__double2hiint(a5) >> 20));
        e = max(e, ivm[6] & (__double2hiint(a6) >> 20));
        e = max(e, ivm[7] & (__double2hiint(a7) >> 20));
        e = max(e, ivm8   & (__double2hiint(a8) >> 20));
        e = DPPMAXI(e, 0x111);   // row_shr:1
        e = DPPMAXI(e, 0x112);   // row_shr:2
        e = DPPMAXI(e, 0x114);   // row_shr:4
        e = DPPMAXI(e, 0x118);   // row_shr:8
        e = DPPMAXI(e, 0x142);   // row_bcast:15
        e = DPPMAXI(e, 0x143);   // row_bcast:31
        const int emax = __builtin_amdgcn_readlane(e, 63);
        int sexp = 2046 - emax;                      // biased exp of 2^(1023-emax)
        sexp = min(max(sexp, 1), 2045);
        const double sc = __hiloint2double(sexp << 20, 0);   // exact power of 2
        tote += 1023 - sexp;
        a0 *= sc; a1 *= sc; a2 *= sc; a3 *= sc; a4 *= sc;
        a5 *= sc; a6 *= sc; a7 *= sc; a8 *= sc;
        n7 *= sc;                                    // keep pipelined value consistent
    };

    // ---- prologue ----
    stage(0, bufs[0]);
    stage(1, bufs[1]);
    stage(2, bufs[2]);
    __builtin_amdgcn_s_waitcnt(0x0F70);  // vmcnt(0): DMA landed; 1 wave, no barrier

    if (lane == 0) {
        a0 = (double)(bufs[0][BLANKc] + EPSF);               // s=0
        if (lab_len > 0) a1 = (double)(bufs[0][c0] + EPSF);  // s=1
    }
    n7 = 0.0;                            // dpp of initial a7 (all zero)

    // prime: row 1 single, pairs (2,3) and (4,5)
    g1(bufs[0] + 1 * Cc, sE);
    gpair(bufs[0] + 2 * Cc, s01);
    gpair(bufs[0] + 4 * Cc, s23);

    // ---- chunk 0: row 1, then pairs (2,3)..(30,31) ----
    expandEven(sE);
    if (1 < in_len) stepfn();
    {
        const float* rb  = bufs[0];
        const float* rbn = bufs[1];
        #pragma unroll
        for (int pr = 0; pr < 15; ++pr) {
            const int r = 2 + 2 * pr;
            float* cur = (pr & 1) ? s23 : s01;
            expandEven(cur); if (r     < in_len) stepfn();
            expandOdd(cur);  if (r + 1 < in_len) stepfn();
            const float* nxt = (r + 4 < CHUNK) ? (rb + (r + 4) * Cc)
                                               : (rbn + (r + 4 - CHUNK) * Cc);
            gpair(nxt, cur);             // prefetch rows r+4, r+5
        }
    }
    rescale();
    __builtin_amdgcn_s_waitcnt(0x0F70);
    stage(3, bufs[0]);

    // ---- chunks 1..31: pair pipeline, rescale once per chunk ----
    for (int k = 1; k < NCHUNK; ++k) {
        const float* rb  = bufs[k % 3];
        const float* rbn = bufs[(k + 1) % 3];   // k=31: dead gathers, safe
        const int tbase = k * CHUNK;
        if (tbase + CHUNK <= in_len) {
            // fast path: whole chunk inside input length, branchless
            #pragma unroll
            for (int pr = 0; pr < 16; ++pr) {
                const int r = 2 * pr;
                float* cur = (pr & 1) ? s23 : s01;
                expandEven(cur); stepfn();
                expandOdd(cur);  stepfn();
                const float* nxt = (r + 4 < CHUNK) ? (rb + (r + 4) * Cc)
                                                   : (rbn + (r + 4 - CHUNK) * Cc);
                gpair(nxt, cur);             // prefetch rows r+4, r+5
            }
        } else {
            #pragma unroll 2
            for (int pr = 0; pr < 16; ++pr) {
                const int r = 2 * pr;
                float* cur = (pr & 1) ? s23 : s01;
                expandEven(cur); if (tbase + r     < in_len) stepfn();
                expandOdd(cur);  if (tbase + r + 1 < in_len) stepfn();
                const float* nxt = (r + 4 < CHUNK) ? (rb + (r + 4) * Cc)
                                                   : (rbn + (r + 4 - CHUNK) * Cc);
                gpair(nxt, cur);
            }
        }
        rescale();
        __builtin_amdgcn_s_waitcnt(0x0F70);     // stage(k+2) landed
        if (k + 3 < NCHUNK) stage(k + 3, bufs[(k + 3) % 3]);
    }

    // ---- epilogue ----
    afin[8 * lane + 0] = a0; afin[8 * lane + 1] = a1;
    afin[8 * lane + 2] = a2; afin[8 * lane + 3] = a3;
    afin[8 * lane + 4] = a4; afin[8 * lane + 5] = a5;
    afin[8 * lane + 6] = a6; afin[8 * lane + 7] = a7;
    if (lane == 63) afin[512] = a8;
    __syncthreads();
    if (lane == 0) {
        const double eb = afin[2 * lab_len];
        const double el = (lab_len > 0) ? afin[2 * lab_len - 1] : 0.0;
        const double loss = -(log(eb + el) + (double)tote * 0.6931471805599453);
        out[b] = (float)loss;
    }
}

extern "C" void kernel_launch(void* const* d_in, const int* in_sizes, int n_in,
                              void* d_out, int out_size, void* d_ws, size_t ws_size,
                              hipStream_t stream) {
    const int*   y_true       = (const int*)d_in[0];
    const float* y_pred       = (const float*)d_in[1];
    const int*   input_length = (const int*)d_in[2];
    const int*   label_length = (const int*)d_in[3];
    float* out = (float*)d_out;

    ctc_kernel<<<Bc, 64, 0, stream>>>(y_true, y_pred, input_length,
                                      label_length, out);
}

// Round 8
// 149.835 us; speedup vs baseline: 2.8154x; 1.0000x over previous
//
#include <hip/hip_runtime.h>

// CTC loss forward, f64 prob-domain with power-of-2 rescaling.
// One WAVE per batch element; lane l holds states 8l..8l+7 (+state 512 on
// lane 63) in f64 regs. No barriers/bpermute in T-loop; neighbor via DPP
// wave_shr:1, pipelined across steps. Two-phase stepfn (all sums, then all
// muls) exposes 9 independent chains. p-values are expanded ONE FULL STEP
// AHEAD into alternating f64 sets (peE/peO), so LDS-gather + cvt latency is
// off the critical path. y_pred staged via global_load_lds into 3x16KB LDS
// buffers; pair-row gathers prefetched 2 pairs ahead, seamless across chunk
// boundaries. Rescale once per 32-step chunk: int-exponent masked max
// (invalid states excluded from anchor, not zeroed -- strictly-forward
// flow), exact 2^-e scaling. f64 window ~1022 bits vs ~800 worst-case need.

#define Bc 64
#define Tc 1024
#define Cc 128
#define Lc 256
#define Sc 513
#define BLANKc 127
#define CHUNK 32
#define NCHUNK (Tc / CHUNK)

constexpr float EPSF = 1e-7f;

#define DPPMAXI(x, ctrl) max(x, __builtin_amdgcn_update_dpp( \
    0, x, ctrl, 0xf, 0xf, true))

__device__ __forceinline__ double dpp_wave_shr1_f64(double x) {
    // lane l <- lane l-1; lane 0 <- 0 (bound_ctrl)
    union { double d; int i[2]; } u, r;
    u.d = x;
    r.i[0] = __builtin_amdgcn_update_dpp(0, u.i[0], 0x138, 0xf, 0xf, true);
    r.i[1] = __builtin_amdgcn_update_dpp(0, u.i[1], 0x138, 0xf, 0xf, true);
    return r.d;
}

__global__ __launch_bounds__(64) void ctc_kernel(
    const int* __restrict__ y_true,        // [B, L]
    const float* __restrict__ y_pred,      // [B, T, C]
    const int* __restrict__ input_length,  // [B, 1]
    const int* __restrict__ label_length,  // [B, 1]
    float* __restrict__ out)               // [B, 1]
{
    const int b = blockIdx.x;
    const int lane = threadIdx.x;          // 0..63, one wave per block

    __shared__ float bufs[3][CHUNK * Cc];  // 3 x 16 KB staged y_pred rows
    __shared__ double afin[Sc];

    const int lab_len = label_length[b];
    const int in_len  = min(input_length[b], Tc);
    const float* yp = y_pred + (size_t)b * Tc * Cc;
    const int* lab = y_true + b * Lc;

    // ---- per-lane static metadata ----
    const int i0 = 4 * lane;
    const int c0 = lab[i0], c1 = lab[i0 + 1], c2 = lab[i0 + 2], c3 = lab[i0 + 3];
    const double sm0 = (lane == 0) ? 0.0
                       : ((c0 != BLANKc && c0 != lab[i0 - 1]) ? 1.0 : 0.0);
    const double sm1 = (c1 != BLANKc && c1 != c0) ? 1.0 : 0.0;
    const double sm2 = (c2 != BLANKc && c2 != c1) ? 1.0 : 0.0;
    const double sm3 = (c3 != BLANKc && c3 != c2) ? 1.0 : 0.0;

    const int S2 = 2 * lab_len + 1;        // validity: state < S2
    int ivm[8];
    #pragma unroll
    for (int j = 0; j < 8; ++j) ivm[j] = (8 * lane + j < S2) ? -1 : 0;
    const int ivm8 = (lane == 63 && 512 < S2) ? -1 : 0;

    auto stage = [&](int k2, float* dstbuf) {
        const float* g = yp + (size_t)k2 * (CHUNK * Cc) + lane * 4;
        #pragma unroll
        for (int i = 0; i < 16; ++i) {
            __builtin_amdgcn_global_load_lds(
                (const __attribute__((address_space(1))) void*)(g + i * 256),
                (__attribute__((address_space(3))) void*)(dstbuf + i * 256),
                16, 0, 0);
        }
    };

    // ---- alpha registers (f64) ----
    double a0 = 0, a1 = 0, a2 = 0, a3 = 0, a4 = 0, a5 = 0, a6 = 0, a7 = 0, a8 = 0;
    double n7 = 0;                         // pipelined dpp(a7)
    int tote = 0;

    // two f64 p-sets, expanded one step ahead of use
    double Eb, E1, E3, E5, E7;             // even-row p's
    double Ob, O1, O3, O5, O7;             // odd-row p's

    // pair slots: even idx = row 2q, odd idx = row 2q+1; slot[q&1] holds pair q
    float s01[10], s23[10];

    auto gpair = [&](const float* rowp, float* sl) {
        sl[0] = rowp[BLANKc]; sl[1] = rowp[BLANKc + Cc];
        sl[2] = rowp[c0];     sl[3] = rowp[c0 + Cc];
        sl[4] = rowp[c1];     sl[5] = rowp[c1 + Cc];
        sl[6] = rowp[c2];     sl[7] = rowp[c2 + Cc];
        sl[8] = rowp[c3];     sl[9] = rowp[c3 + Cc];
    };
    auto expandE = [&](const float* sl) {   // even element of a pair slot
        Eb = (double)(sl[0] + EPSF); E1 = (double)(sl[2] + EPSF);
        E3 = (double)(sl[4] + EPSF); E5 = (double)(sl[6] + EPSF);
        E7 = (double)(sl[8] + EPSF);
    };
    auto expandO = [&](const float* sl) {   // odd element of a pair slot
        Ob = (double)(sl[1] + EPSF); O1 = (double)(sl[3] + EPSF);
        O3 = (double)(sl[5] + EPSF); O5 = (double)(sl[7] + EPSF);
        O7 = (double)(sl[9] + EPSF);
    };
    auto stepE = [&]() {
        const double t8 = a8 + a7;
        const double t7 = __fma_rn(sm3, a5, a7 + a6);
        const double t6 = a6 + a5;
        const double t5 = __fma_rn(sm2, a3, a5 + a4);
        const double t4 = a4 + a3;
        const double t3 = __fma_rn(sm1, a1, a3 + a2);
        const double t2 = a2 + a1;
        const double t1 = __fma_rn(sm0, n7, a1 + a0);
        const double t0 = a0 + n7;
        a7 = t7 * E7;
        n7 = dpp_wave_shr1_f64(a7);
        a8 = t8 * Eb; a6 = t6 * Eb; a5 = t5 * E5; a4 = t4 * Eb;
        a3 = t3 * E3; a2 = t2 * Eb; a1 = t1 * E1; a0 = t0 * Eb;
    };
    auto stepO = [&]() {
        const double t8 = a8 + a7;
        const double t7 = __fma_rn(sm3, a5, a7 + a6);
        const double t6 = a6 + a5;
        const double t5 = __fma_rn(sm2, a3, a5 + a4);
        const double t4 = a4 + a3;
        const double t3 = __fma_rn(sm1, a1, a3 + a2);
        const double t2 = a2 + a1;
        const double t1 = __fma_rn(sm0, n7, a1 + a0);
        const double t0 = a0 + n7;
        a7 = t7 * O7;
        n7 = dpp_wave_shr1_f64(a7);
        a8 = t8 * Ob; a6 = t6 * Ob; a5 = t5 * O5; a4 = t4 * Ob;
        a3 = t3 * O3; a2 = t2 * Ob; a1 = t1 * O1; a0 = t0 * Ob;
    };
    auto rescale = [&]() {
        int e;
        e =        ivm[0] & (__double2hiint(a0) >> 20);
        e = max(e, ivm[1] & (__double2hiint(a1) >> 20));
        e = max(e, ivm[2] & (__double2hiint(a2) >> 20));
        e = max(e, ivm[3] & (__double2hiint(a3) >> 20));
        e = max(e, ivm[4] & (__double2hiint(a4) >> 20));
        e = max(e, ivm[5] & (__double2hiint(a5) >> 20));
        e = max(e, ivm[6] & (__double2hiint(a6) >> 20));
        e = max(e, ivm[7] & (__double2hiint(a7) >> 20));
        e = max(e, ivm8   & (__double2hiint(a8) >> 20));
        e = DPPMAXI(e, 0x111);   // row_shr:1
        e = DPPMAXI(e, 0x112);   // row_shr:2
        e = DPPMAXI(e, 0x114);   // row_shr:4
        e = DPPMAXI(e, 0x118);   // row_shr:8
        e = DPPMAXI(e, 0x142);   // row_bcast:15
        e = DPPMAXI(e, 0x143);   // row_bcast:31
        const int emax = __builtin_amdgcn_readlane(e, 63);
        int sexp = 2046 - emax;                      // biased exp of 2^(1023-emax)
        sexp = min(max(sexp, 1), 2045);
        const double sc = __hiloint2double(sexp << 20, 0);   // exact power of 2
        tote += 1023 - sexp;
        a0 *= sc; a1 *= sc; a2 *= sc; a3 *= sc; a4 *= sc;
        a5 *= sc; a6 *= sc; a7 *= sc; a8 *= sc;
        n7 *= sc;
    };

    // ---- prologue ----
    stage(0, bufs[0]);
    stage(1, bufs[1]);
    stage(2, bufs[2]);
    __builtin_amdgcn_s_waitcnt(0x0F70);  // vmcnt(0): DMA landed; 1 wave, no barrier

    if (lane == 0) {
        a0 = (double)(bufs[0][BLANKc] + EPSF);               // s=0
        if (lab_len > 0) a1 = (double)(bufs[0][c0] + EPSF);  // s=1
    }

    // prime slots & pe pipeline:
    // pair q=1 (rows 2,3) -> slot1; pair q=2 (rows 4,5) -> slot0
    gpair(bufs[0] + 2 * Cc, s23);
    gpair(bufs[0] + 4 * Cc, s01);
    {   // row 1 direct -> odd set; row 2 -> even set
        const float* r1 = bufs[0] + 1 * Cc;
        Ob = (double)(r1[BLANKc] + EPSF); O1 = (double)(r1[c0] + EPSF);
        O3 = (double)(r1[c1] + EPSF);     O5 = (double)(r1[c2] + EPSF);
        O7 = (double)(r1[c3] + EPSF);
    }
    expandE(s23);                        // row 2

    // ---- step t=1 (lone odd step) ----
    if (1 < in_len) stepO();
    expandO(s23);                        // row 3 for t=3

    // ---- chunk 0: pairs q=1..15 (rows 2..31) ----
    {
        const float* rb  = bufs[0];
        const float* rbn = bufs[1];
        #pragma unroll
        for (int qi = 1; qi < 16; ++qi) {
            const int rr = 2 * qi;
            if (rr < in_len) stepE();
            expandE((qi & 1) ? s01 : s23);     // row rr+2 from slot[(qi+1)&1]
            if (rr + 1 < in_len) stepO();
            expandO((qi & 1) ? s01 : s23);     // row rr+3
            const float* nxt = (rr + 4 < CHUNK) ? (rb + (rr + 4) * Cc)
                                                : (rbn + (rr + 4 - CHUNK) * Cc);
            gpair(nxt, (qi & 1) ? s23 : s01);  // pair qi+2 -> slot[qi&1]
        }
    }
    rescale();
    __builtin_amdgcn_s_waitcnt(0x0F70);
    stage(3, bufs[0]);

    // ---- chunks 1..31: unified pair pipeline ----
    for (int k = 1; k < NCHUNK; ++k) {
        const float* rb  = bufs[k % 3];
        const float* rbn = bufs[(k + 1) % 3];   // k=31: dead reads, safe
        const int tbase = k * CHUNK;
        if (tbase + CHUNK <= in_len) {
            #pragma unroll
            for (int qi = 0; qi < 16; ++qi) {
                const int rr = 2 * qi;
                stepE();
                expandE((qi & 1) ? s01 : s23);
                stepO();
                expandO((qi & 1) ? s01 : s23);
                const float* nxt = (rr + 4 < CHUNK) ? (rb + (rr + 4) * Cc)
                                                    : (rbn + (rr + 4 - CHUNK) * Cc);
                gpair(nxt, (qi & 1) ? s23 : s01);
            }
        } else {
            #pragma unroll 2
            for (int qi = 0; qi < 16; ++qi) {
                const int rr = 2 * qi;
                if (tbase + rr < in_len) stepE();
                expandE((qi & 1) ? s01 : s23);
                if (tbase + rr + 1 < in_len) stepO();
                expandO((qi & 1) ? s01 : s23);
                const float* nxt = (rr + 4 < CHUNK) ? (rb + (rr + 4) * Cc)
                                                    : (rbn + (rr + 4 - CHUNK) * Cc);
                gpair(nxt, (qi & 1) ? s23 : s01);
            }
        }
        rescale();
        __builtin_amdgcn_s_waitcnt(0x0F70);     // stage(k+2) landed
        if (k + 3 < NCHUNK) stage(k + 3, bufs[(k + 3) % 3]);
    }

    // ---- epilogue ----
    afin[8 * lane + 0] = a0; afin[8 * lane + 1] = a1;
    afin[8 * lane + 2] = a2; afin[8 * lane + 3] = a3;
    afin[8 * lane + 4] = a4; afin[8 * lane + 5] = a5;
    afin[8 * lane + 6] = a6; afin[8 * lane + 7] = a7;
    if (lane == 63) afin[512] = a8;
    __syncthreads();
    if (lane == 0) {
        const double eb = afin[2 * lab_len];
        const double el = (lab_len > 0) ? afin[2 * lab_len - 1] : 0.0;
        const double loss = -(log(eb + el) + (double)tote * 0.6931471805599453);
        out[b] = (float)loss;
    }
}

extern "C" void kernel_launch(void* const* d_in, const int* in_sizes, int n_in,
                              void* d_out, int out_size, void* d_ws, size_t ws_size,
                              hipStream_t stream) {
    const int*   y_true       = (const int*)d_in[0];
    const float* y_pred       = (const float*)d_in[1];
    const int*   input_length = (const int*)d_in[2];
    const int*   label_length = (const int*)d_in[3];
    float* out = (float*)d_out;

    ctc_kernel<<<Bc, 64, 0, stream>>>(y_true, y_pred, input_length,
                                      label_length, out);
}